// Round 1
// baseline (3467.430 us; speedup 1.0000x reference)
//
#include <hip/hip_runtime.h>
#include <hip/hip_bf16.h>
#include <math.h>

#define B_  2
#define L_  2048
#define D_  2048
#define H_  16
#define HD_ 128
#define EPS_ 1e-5f

// ---------------------------------------------------------------------------
// Projection GEMM: Out[m,n] = sum_k x[m,k] * W[n,k]   (torch Linear, y=xW^T)
// Written to [B,H,L,HD] layout.  grid.z selects Q/K/V.
// ---------------------------------------------------------------------------
#define PBM 64
#define PBN 64
#define PBK 16

__global__ __launch_bounds__(256) void proj_kernel(
    const float* __restrict__ x,
    const float* __restrict__ Wq, const float* __restrict__ Wk,
    const float* __restrict__ Wv,
    float* __restrict__ Qo, float* __restrict__ Ko, float* __restrict__ Vo)
{
    const float* W   = (blockIdx.z == 0) ? Wq : (blockIdx.z == 1 ? Wk : Wv);
    float*       Out = (blockIdx.z == 0) ? Qo : (blockIdx.z == 1 ? Ko : Vo);

    __shared__ float As[PBK][PBM + 4];   // stride 68 words: 2-way max on store, cf on read
    __shared__ float Bs[PBK][PBN + 4];

    const int t  = threadIdx.x;
    const int tx = t & 15, ty = t >> 4;
    const int m0 = blockIdx.y * PBM;
    const int n0 = blockIdx.x * PBN;
    const int lrow = t >> 2;            // 0..63
    const int lkq  = (t & 3) * 4;       // 0,4,8,12

    float c[4][4] = {};

    for (int k0 = 0; k0 < D_; k0 += PBK) {
        float4 av = *(const float4*)&x[(size_t)(m0 + lrow) * D_ + k0 + lkq];
        float4 bv = *(const float4*)&W[(size_t)(n0 + lrow) * D_ + k0 + lkq];
        As[lkq + 0][lrow] = av.x; As[lkq + 1][lrow] = av.y;
        As[lkq + 2][lrow] = av.z; As[lkq + 3][lrow] = av.w;
        Bs[lkq + 0][lrow] = bv.x; Bs[lkq + 1][lrow] = bv.y;
        Bs[lkq + 2][lrow] = bv.z; Bs[lkq + 3][lrow] = bv.w;
        __syncthreads();
        #pragma unroll
        for (int k = 0; k < PBK; ++k) {
            float4 a4 = *(const float4*)&As[k][4 * ty];
            float4 b4 = *(const float4*)&Bs[k][4 * tx];
            c[0][0] += a4.x * b4.x; c[0][1] += a4.x * b4.y; c[0][2] += a4.x * b4.z; c[0][3] += a4.x * b4.w;
            c[1][0] += a4.y * b4.x; c[1][1] += a4.y * b4.y; c[1][2] += a4.y * b4.z; c[1][3] += a4.y * b4.w;
            c[2][0] += a4.z * b4.x; c[2][1] += a4.z * b4.y; c[2][2] += a4.z * b4.z; c[2][3] += a4.z * b4.w;
            c[3][0] += a4.w * b4.x; c[3][1] += a4.w * b4.y; c[3][2] += a4.w * b4.z; c[3][3] += a4.w * b4.w;
        }
        __syncthreads();
    }

    // write to [B,H,L,HD]
    #pragma unroll
    for (int i = 0; i < 4; ++i) {
        const int m = m0 + 4 * ty + i;
        const int b = m >> 11;           // m / L_
        const int l = m & (L_ - 1);
        const int n = n0 + 4 * tx;
        const int h  = n >> 7;           // n / HD_
        const int hd = n & (HD_ - 1);
        float4 w4 = make_float4(c[i][0], c[i][1], c[i][2], c[i][3]);
        *(float4*)&Out[((size_t)(b * H_ + h) * L_ + l) * HD_ + hd] = w4;
    }
}

// ---------------------------------------------------------------------------
// Retention: out[b,h,i,:] = sum_{j<=i} (q_i.k_j)*scale*gamma^(i-j) * v_j
// One block = (b,h, 32-row tile).  128 threads: thread owns output dim d=tid.
// ---------------------------------------------------------------------------
#define TR 32
#define TJ 32
#define QPAD (HD_ + 4)   // 132 words, 16B aligned, breaks 32-way conflicts
#define SPAD (TJ + 4)    // 36 words

__global__ __launch_bounds__(128) void retn_kernel(
    const float* __restrict__ Q, const float* __restrict__ K,
    const float* __restrict__ V, const float* __restrict__ gl,
    float* __restrict__ out)
{
    const int bh = blockIdx.y;
    const int b  = bh >> 4;
    const int h  = bh & (H_ - 1);
    // heavy blocks (large r0) first for load balance
    const int r0 = (gridDim.x - 1 - blockIdx.x) * TR;
    const int tid = threadIdx.x;

    const float gamma = 1.f / (1.f + __expf(-gl[h]));
    const float lg    = __logf(gamma);
    const float scale = 0.08838834764831845f;   // 128^-0.5

    __shared__ float Qs[TR][QPAD];
    __shared__ float Ks[TJ][QPAD];
    __shared__ float Vs[TJ][QPAD];
    __shared__ float Ss[TR][SPAD];

    const size_t base = (size_t)bh * L_ * HD_;

    #pragma unroll 8
    for (int r = 0; r < TR; ++r)
        Qs[r][tid] = Q[base + (size_t)(r0 + r) * HD_ + tid];

    float acc[TR];
    #pragma unroll
    for (int r = 0; r < TR; ++r) acc[r] = 0.f;

    const int r_id = tid & 31;
    const int jb   = (tid >> 5) * 8;
    const int i_glob = r0 + r_id;

    for (int j0 = 0; j0 <= r0 + TR - 1; j0 += TJ) {
        __syncthreads();   // previous tile's compute done before overwrite
        #pragma unroll 8
        for (int jj = 0; jj < TJ; ++jj) {
            Ks[jj][tid] = K[base + (size_t)(j0 + jj) * HD_ + tid];
            Vs[jj][tid] = V[base + (size_t)(j0 + jj) * HD_ + tid];
        }
        __syncthreads();

        // scores: thread computes rows r_id, cols jb..jb+7
        float s[8] = {0.f, 0.f, 0.f, 0.f, 0.f, 0.f, 0.f, 0.f};
        for (int kq = 0; kq < HD_; kq += 4) {
            float4 q4 = *(const float4*)&Qs[r_id][kq];
            #pragma unroll
            for (int q = 0; q < 8; ++q) {
                float4 k4 = *(const float4*)&Ks[jb + q][kq];
                s[q] += q4.x * k4.x + q4.y * k4.y + q4.z * k4.z + q4.w * k4.w;
            }
        }
        #pragma unroll
        for (int q = 0; q < 8; ++q) {
            const int j = j0 + jb + q;
            float dec = (j <= i_glob) ? __expf(lg * (float)(i_glob - j)) * scale : 0.f;
            Ss[r_id][jb + q] = s[q] * dec;
        }
        __syncthreads();

        // accumulate: acc[r] += Ss[r][jj] * Vs[jj][tid]
        for (int jq = 0; jq < TJ; jq += 4) {
            const float v0 = Vs[jq + 0][tid];
            const float v1 = Vs[jq + 1][tid];
            const float v2 = Vs[jq + 2][tid];
            const float v3 = Vs[jq + 3][tid];
            #pragma unroll
            for (int r = 0; r < TR; ++r) {
                float4 s4 = *(const float4*)&Ss[r][jq];   // uniform addr: broadcast
                acc[r] += s4.x * v0 + s4.y * v1 + s4.z * v2 + s4.w * v3;
            }
        }
    }

    #pragma unroll 8
    for (int r = 0; r < TR; ++r)
        out[((size_t)(b * L_ + r0 + r)) * D_ + h * HD_ + tid] = acc[r];
}

// ---------------------------------------------------------------------------
// GroupNorm over (L,HD) per (b,h), in place on d_out, then affine.
// ---------------------------------------------------------------------------
__global__ __launch_bounds__(1024) void gn_kernel(
    float* __restrict__ out,
    const float* __restrict__ gw, const float* __restrict__ gb)
{
    const int bh = blockIdx.x;
    const int b  = bh >> 4;
    const int h  = bh & (H_ - 1);
    const int t  = threadIdx.x;
    const int NPER = L_ * HD_;     // 262144

    float s = 0.f, sq = 0.f;
    for (int n = t; n < NPER; n += 1024) {
        const int l = n >> 7, d = n & (HD_ - 1);
        float v = out[((size_t)(b * L_ + l)) * D_ + h * HD_ + d];
        s += v; sq += v * v;
    }
    __shared__ float rs[16], rq[16];
    #pragma unroll
    for (int off = 32; off > 0; off >>= 1) {
        s  += __shfl_down(s, off);
        sq += __shfl_down(sq, off);
    }
    const int wave = t >> 6, lane = t & 63;
    if (lane == 0) { rs[wave] = s; rq[wave] = sq; }
    __syncthreads();
    if (t == 0) {
        float S = 0.f, SQ = 0.f;
        #pragma unroll
        for (int w = 0; w < 16; ++w) { S += rs[w]; SQ += rq[w]; }
        const float mean = S / (float)NPER;
        float var = SQ / (float)NPER - mean * mean;
        if (var < 0.f) var = 0.f;
        rs[0] = mean;
        rq[0] = rsqrtf(var + EPS_);
    }
    __syncthreads();
    const float mean = rs[0], rstd = rq[0];
    for (int n = t; n < NPER; n += 1024) {
        const int l = n >> 7, d = n & (HD_ - 1);
        const size_t idx = ((size_t)(b * L_ + l)) * D_ + h * HD_ + d;
        float v = out[idx];
        out[idx] = (v - mean) * rstd * gw[h * HD_ + d] + gb[h * HD_ + d];
    }
}

// ---------------------------------------------------------------------------
extern "C" void kernel_launch(void* const* d_in, const int* in_sizes, int n_in,
                              void* d_out, int out_size, void* d_ws, size_t ws_size,
                              hipStream_t stream) {
    const float* x  = (const float*)d_in[0];
    const float* Wq = (const float*)d_in[1];
    const float* Wk = (const float*)d_in[2];
    const float* Wv = (const float*)d_in[3];
    const float* gl = (const float*)d_in[4];
    const float* gw = (const float*)d_in[5];
    const float* gb = (const float*)d_in[6];
    float* out = (float*)d_out;

    const size_t per = (size_t)B_ * H_ * L_ * HD_;   // 8,388,608 floats
    float* Qb = (float*)d_ws;
    float* Kb = Qb + per;
    float* Vb = Kb + per;

    dim3 pgrid(D_ / PBN, (B_ * L_) / PBM, 3);
    proj_kernel<<<pgrid, 256, 0, stream>>>(x, Wq, Wk, Wv, Qb, Kb, Vb);

    dim3 rgrid(L_ / TR, B_ * H_);
    retn_kernel<<<rgrid, 128, 0, stream>>>(Qb, Kb, Vb, gl, out);

    gn_kernel<<<dim3(B_ * H_), 1024, 0, stream>>>(out, gw, gb);
}

// Round 2
// 398.918 us; speedup vs baseline: 8.6921x; 8.6921x over previous
//
#include <hip/hip_runtime.h>
#include <hip/hip_bf16.h>
#include <math.h>

#define B_  2
#define L_  2048
#define D_  2048
#define H_  16
#define HD_ 128
#define EPS_ 1e-5f

typedef __attribute__((ext_vector_type(8)))  short short8;
typedef __attribute__((ext_vector_type(4)))  float f32x4;
typedef __attribute__((ext_vector_type(16))) float f32x16;

static __device__ inline unsigned short bfb(float x) {
    __hip_bfloat16 h = __float2bfloat16(x);
    unsigned short s;
    __builtin_memcpy(&s, &h, 2);
    return s;
}
static __device__ inline unsigned pk2(float a, float b) {
    return (unsigned)bfb(a) | ((unsigned)bfb(b) << 16);
}

// ---------------------------------------------------------------------------
// cast f32 -> bf16, vectorized (float4 -> 4 bf16)
// ---------------------------------------------------------------------------
__global__ __launch_bounds__(256) void cast_kernel(
    const float* __restrict__ src, __hip_bfloat16* __restrict__ dst, int n4)
{
    int i = blockIdx.x * 256 + threadIdx.x;
    const int st = gridDim.x * 256;
    for (; i < n4; i += st) {
        float4 v = ((const float4*)src)[i];
        uint2 r;
        r.x = pk2(v.x, v.y);
        r.y = pk2(v.z, v.w);
        ((uint2*)dst)[i] = r;
    }
}

// ---------------------------------------------------------------------------
// Projection GEMM (bf16 MFMA): Out[m,n] = sum_k X[m,k] * W[n,k]
// 128x128 tile, BK=32, 4 waves (each 64x64 = 4x4 frags of 16x16x32).
// Output written bf16 to [B,H,L,HD].
// ---------------------------------------------------------------------------
__global__ __launch_bounds__(256) void proj_bf16(
    const __hip_bfloat16* __restrict__ X,
    const __hip_bfloat16* __restrict__ Wqb, const __hip_bfloat16* __restrict__ Wkb,
    const __hip_bfloat16* __restrict__ Wvb,
    __hip_bfloat16* __restrict__ Qo, __hip_bfloat16* __restrict__ Ko,
    __hip_bfloat16* __restrict__ Vo)
{
    const __hip_bfloat16* W = (blockIdx.z == 0) ? Wqb : (blockIdx.z == 1 ? Wkb : Wvb);
    __hip_bfloat16*       O = (blockIdx.z == 0) ? Qo  : (blockIdx.z == 1 ? Ko  : Vo);

    __shared__ __align__(16) char Al[128 * 32 * 2];   // [row][k] bf16 linear
    __shared__ __align__(16) char Bl[128 * 32 * 2];

    const int t  = threadIdx.x;
    const int w  = t >> 6, l = t & 63;
    const int li = l & 15, hi4 = l >> 4;
    const int wr = w >> 1, wc = w & 1;
    const int m0 = blockIdx.y * 128;
    const int n0 = blockIdx.x * 128;

    f32x4 acc[4][4];
    #pragma unroll
    for (int i = 0; i < 4; ++i)
        #pragma unroll
        for (int j = 0; j < 4; ++j)
            #pragma unroll
            for (int r = 0; r < 4; ++r) acc[i][j][r] = 0.f;

    for (int k0 = 0; k0 < D_; k0 += 32) {
        if (k0) __syncthreads();
        #pragma unroll
        for (int p = 0; p < 2; ++p) {
            const int tt = p * 256 + t;
            const int row = tt >> 2, kg = tt & 3;
            *(int4*)(Al + tt * 16) =
                *(const int4*)(X + (size_t)(m0 + row) * D_ + k0 + kg * 8);
            *(int4*)(Bl + tt * 16) =
                *(const int4*)(W + (size_t)(n0 + row) * D_ + k0 + kg * 8);
        }
        __syncthreads();

        short8 af[4], bf[4];
        #pragma unroll
        for (int mi = 0; mi < 4; ++mi)
            af[mi] = *(const short8*)(Al + (wr * 64 + mi * 16 + li) * 64 + hi4 * 16);
        #pragma unroll
        for (int ni = 0; ni < 4; ++ni)
            bf[ni] = *(const short8*)(Bl + (wc * 64 + ni * 16 + li) * 64 + hi4 * 16);
        #pragma unroll
        for (int mi = 0; mi < 4; ++mi)
            #pragma unroll
            for (int ni = 0; ni < 4; ++ni)
                acc[mi][ni] = __builtin_amdgcn_mfma_f32_16x16x32_bf16(
                    af[mi], bf[ni], acc[mi][ni], 0, 0, 0);
    }

    // epilogue: C[r]: row = (l>>4)*4 + r, col = l&15  (verified layout)
    #pragma unroll
    for (int mi = 0; mi < 4; ++mi) {
        #pragma unroll
        for (int ni = 0; ni < 4; ++ni) {
            const int n  = n0 + wc * 64 + ni * 16 + li;
            const int h  = n >> 7, hd = n & (HD_ - 1);
            #pragma unroll
            for (int r = 0; r < 4; ++r) {
                const int m = m0 + wr * 64 + mi * 16 + hi4 * 4 + r;
                const int b = m >> 11, ml = m & (L_ - 1);
                O[((size_t)(b * H_ + h) * L_ + ml) * HD_ + hd] =
                    __float2bfloat16(acc[mi][ni][r]);
            }
        }
    }
}

// ---------------------------------------------------------------------------
// Retention (bf16 MFMA): out[b,h,i,:] = sum_{j<=i} (q_i.k_j)*scale*g^(i-j) v_j
// Block = 4 waves x 32 Q-rows (QBLK=128). KV tiles of 32.
// S^T = mfma(K, Q)  (lane owns column i); decay elementwise; P-frags via
// pack+shfl_xor(32); PV = mfma(P, V) with V staged transposed in LDS.
// ---------------------------------------------------------------------------
__global__ __launch_bounds__(256) void retn_kernel(
    const __hip_bfloat16* __restrict__ Qb, const __hip_bfloat16* __restrict__ Kb,
    const __hip_bfloat16* __restrict__ Vb, const float* __restrict__ gl,
    float* __restrict__ out)
{
    const int bid = blockIdx.x;
    const int m   = 15 - (bid >> 5);        // heavy blocks dispatched first
    const int bh  = bid & 31;
    const int b   = bh >> 4, h = bh & (H_ - 1);
    const int t   = threadIdx.x;
    const int w   = t >> 6, l = t & 63;
    const int li  = l & 31, hi = l >> 5;

    const float gamma = 1.f / (1.f + __expf(-gl[h]));
    const float lg2   = __log2f(gamma);
    const float scale = 0.08838834764831845f;   // 128^-0.5

    __shared__ __align__(16) char Kls[32 * 128 * 2];            // XOR-swizzled rows
    __shared__ __align__(16) unsigned short Vt[128 * 40];       // [d][j] padded

    const size_t base = (size_t)bh * (L_ * HD_);
    const int i0 = m * 128 + w * 32;          // this wave's first Q row

    // hoist Q fragments: B-operand for S^T (col = li, k = hd slice)
    short8 qf[8];
    {
        const __hip_bfloat16* qrow = Qb + base + (size_t)(i0 + li) * HD_;
        #pragma unroll
        for (int s = 0; s < 8; ++s)
            qf[s] = *(const short8*)(qrow + s * 16 + hi * 8);
    }

    // per-lane decay factors gamma^(i_loc - j_loc) for the 16 C-regs
    float df[16];
    #pragma unroll
    for (int r = 0; r < 16; ++r) {
        const int jl = (r & 3) + 8 * (r >> 2) + 4 * hi;
        df[r] = exp2f(lg2 * (float)(li - jl));
    }

    f32x16 acc[4];
    #pragma unroll
    for (int c = 0; c < 4; ++c)
        #pragma unroll
        for (int r = 0; r < 16; ++r) acc[c][r] = 0.f;

    const int jmax = m * 128 + 96;            // block max wave i0
    for (int j0 = 0; j0 <= jmax; j0 += 32) {
        if (j0) __syncthreads();
        // stage K (swizzled) and V (transposed), 2 passes x 256 thr x 16B
        #pragma unroll
        for (int p = 0; p < 2; ++p) {
            const int tt = p * 256 + t;
            const int jr = tt >> 4, seg = tt & 15;
            int4 kv = *(const int4*)(Kb + base + (size_t)(j0 + jr) * HD_ + seg * 8);
            *(int4*)(Kls + jr * 256 + ((seg * 16) ^ ((jr & 7) << 4))) = kv;
            int4 vv = *(const int4*)(Vb + base + (size_t)(j0 + jr) * HD_ + seg * 8);
            const unsigned short* pv = (const unsigned short*)&vv;
            #pragma unroll
            for (int e = 0; e < 8; ++e)
                Vt[(seg * 8 + e) * 40 + jr] = pv[e];
        }
        __syncthreads();

        if (j0 > i0) continue;                // causal skip (barriers stay uniform)

        // QK^T: S^T[j,i], j = C-rows, i = C-col (= li)
        f32x16 c;
        #pragma unroll
        for (int r = 0; r < 16; ++r) c[r] = 0.f;
        #pragma unroll
        for (int s = 0; s < 8; ++s) {
            short8 kf = *(const short8*)(Kls + li * 256 +
                                         ((s * 32 + hi * 16) ^ ((li & 7) << 4)));
            c = __builtin_amdgcn_mfma_f32_32x32x16_bf16(kf, qf[s], c, 0, 0, 0);
        }

        // decay (+ diagonal mask)
        float p[16];
        const float bt = exp2f(lg2 * (float)(i0 - j0)) * scale;
        if (j0 == i0) {
            #pragma unroll
            for (int r = 0; r < 16; ++r) {
                const int jl = (r & 3) + 8 * (r >> 2) + 4 * hi;
                p[r] = (jl <= li) ? c[r] * (df[r] * bt) : 0.f;
            }
        } else {
            #pragma unroll
            for (int r = 0; r < 16; ++r) p[r] = c[r] * (df[r] * bt);
        }

        // two k-slices (j 0..15 from regs 0..7, j 16..31 from regs 8..15)
        #pragma unroll
        for (int sl = 0; sl < 2; ++sl) {
            const int o = sl * 8;
            unsigned pk01 = pk2(p[o + 0], p[o + 1]);
            unsigned pk23 = pk2(p[o + 2], p[o + 3]);
            unsigned pk45 = pk2(p[o + 4], p[o + 5]);
            unsigned pk67 = pk2(p[o + 6], p[o + 7]);
            unsigned x01 = (unsigned)__shfl_xor((int)pk01, 32);
            unsigned x23 = (unsigned)__shfl_xor((int)pk23, 32);
            unsigned x45 = (unsigned)__shfl_xor((int)pk45, 32);
            unsigned x67 = (unsigned)__shfl_xor((int)pk67, 32);
            union { short8 v; unsigned u[4]; } pf;
            pf.u[0] = hi ? x45 : pk01;
            pf.u[1] = hi ? x67 : pk23;
            pf.u[2] = hi ? pk45 : x01;
            pf.u[3] = hi ? pk67 : x23;
            #pragma unroll
            for (int cch = 0; cch < 4; ++cch) {
                short8 vf = *(const short8*)(Vt + (cch * 32 + li) * 40 + sl * 16 + hi * 8);
                acc[cch] = __builtin_amdgcn_mfma_f32_32x32x16_bf16(
                    pf.v, vf, acc[cch], 0, 0, 0);
            }
        }
    }

    // epilogue: acc[cch] C-layout: col d = cch*32+li, row = (r&3)+8*(r>>2)+4*hi
    #pragma unroll
    for (int cch = 0; cch < 4; ++cch) {
        #pragma unroll
        for (int r = 0; r < 16; ++r) {
            const int row = (r & 3) + 8 * (r >> 2) + 4 * hi;
            out[(size_t)(b * L_ + i0 + row) * D_ + h * HD_ + cch * 32 + li] =
                acc[cch][r];
        }
    }
}

// ---------------------------------------------------------------------------
// GroupNorm over (L,HD) per (b,h), in place on d_out, then affine.
// ---------------------------------------------------------------------------
__global__ __launch_bounds__(1024) void gn_kernel(
    float* __restrict__ out,
    const float* __restrict__ gw, const float* __restrict__ gb)
{
    const int bh = blockIdx.x;
    const int b  = bh >> 4;
    const int h  = bh & (H_ - 1);
    const int t  = threadIdx.x;
    const int NPER = L_ * HD_;

    float s = 0.f, sq = 0.f;
    for (int n = t; n < NPER; n += 1024) {
        const int ll = n >> 7, d = n & (HD_ - 1);
        float v = out[((size_t)(b * L_ + ll)) * D_ + h * HD_ + d];
        s += v; sq += v * v;
    }
    __shared__ float rs[16], rq[16];
    #pragma unroll
    for (int off = 32; off > 0; off >>= 1) {
        s  += __shfl_down(s, off);
        sq += __shfl_down(sq, off);
    }
    const int wave = t >> 6, lane = t & 63;
    if (lane == 0) { rs[wave] = s; rq[wave] = sq; }
    __syncthreads();
    if (t == 0) {
        float S = 0.f, SQ = 0.f;
        #pragma unroll
        for (int ww = 0; ww < 16; ++ww) { S += rs[ww]; SQ += rq[ww]; }
        const float mean = S / (float)NPER;
        float var = SQ / (float)NPER - mean * mean;
        if (var < 0.f) var = 0.f;
        rs[0] = mean;
        rq[0] = rsqrtf(var + EPS_);
    }
    __syncthreads();
    const float mean = rs[0], rstd = rq[0];
    for (int n = t; n < NPER; n += 1024) {
        const int ll = n >> 7, d = n & (HD_ - 1);
        const size_t idx = ((size_t)(b * L_ + ll)) * D_ + h * HD_ + d;
        float v = out[idx];
        out[idx] = (v - mean) * rstd * gw[h * HD_ + d] + gb[h * HD_ + d];
    }
}

// ---------------------------------------------------------------------------
extern "C" void kernel_launch(void* const* d_in, const int* in_sizes, int n_in,
                              void* d_out, int out_size, void* d_ws, size_t ws_size,
                              hipStream_t stream) {
    const float* x  = (const float*)d_in[0];
    const float* Wq = (const float*)d_in[1];
    const float* Wk = (const float*)d_in[2];
    const float* Wv = (const float*)d_in[3];
    const float* gl = (const float*)d_in[4];
    const float* gw = (const float*)d_in[5];
    const float* gb = (const float*)d_in[6];
    float* out = (float*)d_out;

    __hip_bfloat16* ws = (__hip_bfloat16*)d_ws;
    __hip_bfloat16* xb  = ws;                    // 8,388,608
    __hip_bfloat16* Wqb = xb  + 8388608;         // 4,194,304
    __hip_bfloat16* Wkb = Wqb + 4194304;
    __hip_bfloat16* Wvb = Wkb + 4194304;
    __hip_bfloat16* Qbf = Wvb + 4194304;         // 8,388,608 each
    __hip_bfloat16* Kbf = Qbf + 8388608;
    __hip_bfloat16* Vbf = Kbf + 8388608;

    cast_kernel<<<2048, 256, 0, stream>>>(x,  xb,  8388608 / 4);
    cast_kernel<<<1024, 256, 0, stream>>>(Wq, Wqb, 4194304 / 4);
    cast_kernel<<<1024, 256, 0, stream>>>(Wk, Wkb, 4194304 / 4);
    cast_kernel<<<1024, 256, 0, stream>>>(Wv, Wvb, 4194304 / 4);

    dim3 pgrid(D_ / 128, (B_ * L_) / 128, 3);
    proj_bf16<<<pgrid, 256, 0, stream>>>(xb, Wqb, Wkb, Wvb, Qbf, Kbf, Vbf);

    retn_kernel<<<dim3(512), 256, 0, stream>>>(Qbf, Kbf, Vbf, gl, out);

    gn_kernel<<<dim3(B_ * H_), 1024, 0, stream>>>(out, gw, gb);
}

// Round 4
// 280.356 us; speedup vs baseline: 12.3680x; 1.4229x over previous
//
#include <hip/hip_runtime.h>
#include <hip/hip_bf16.h>
#include <math.h>

#define B_  2
#define L_  2048
#define D_  2048
#define H_  16
#define HD_ 128
#define EPS_ 1e-5f

typedef __attribute__((ext_vector_type(8)))  short short8;
typedef __attribute__((ext_vector_type(4)))  float f32x4;
typedef __attribute__((ext_vector_type(16))) float f32x16;

static __device__ inline unsigned short bfb(float x) {
    __hip_bfloat16 h = __float2bfloat16(x);
    unsigned short s;
    __builtin_memcpy(&s, &h, 2);
    return s;
}
static __device__ inline unsigned pk2(float a, float b) {
    return (unsigned)bfb(a) | ((unsigned)bfb(b) << 16);
}

// direct-to-LDS 16B copy: LDS dest = wave-uniform base + lane*16
static __device__ __forceinline__ void gld_lds16(const void* g, void* l) {
    __builtin_amdgcn_global_load_lds(
        (const __attribute__((address_space(1))) unsigned int*)g,
        (__attribute__((address_space(3))) unsigned int*)l,
        16, 0, 0);
}

// ---------------------------------------------------------------------------
// fused cast f32 -> bf16 for x, Wq, Wk, Wv (dsts contiguous in ws)
// ---------------------------------------------------------------------------
#define XN4 2097152              // 8388608/4
#define WN4 1048576              // 4194304/4
#define TOT4 (XN4 + 3 * WN4)     // 5242880

__global__ __launch_bounds__(256) void cast4_kernel(
    const float* __restrict__ x,  const float* __restrict__ Wq,
    const float* __restrict__ Wk, const float* __restrict__ Wv,
    __hip_bfloat16* __restrict__ dst)
{
    int i = blockIdx.x * 256 + threadIdx.x;
    const int st = gridDim.x * 256;
    for (; i < TOT4; i += st) {
        const float* s;
        int off;
        if (i < XN4)                { s = x;  off = i; }
        else if (i < XN4 + WN4)     { s = Wq; off = i - XN4; }
        else if (i < XN4 + 2 * WN4) { s = Wk; off = i - XN4 - WN4; }
        else                        { s = Wv; off = i - XN4 - 2 * WN4; }
        float4 v = ((const float4*)s)[off];
        uint2 r;
        r.x = pk2(v.x, v.y);
        r.y = pk2(v.z, v.w);
        ((uint2*)dst)[i] = r;
    }
}

// ---------------------------------------------------------------------------
// Projection GEMM (bf16 MFMA): Out[m,n] = sum_k X[m,k] * W[n,k]
// 128x128 tile, BK=64, 4 waves, global_load_lds staging.
// LDS linear dest + pre-swizzled global source + XOR-swizzled reads (rule 21):
//   LDS[row][cb] = global[row][cb ^ ((row&7)<<4)]  (byte units, 128B rows)
// ---------------------------------------------------------------------------
__global__ __launch_bounds__(256) void proj_bf16(
    const __hip_bfloat16* __restrict__ X,
    const __hip_bfloat16* __restrict__ Wqb, const __hip_bfloat16* __restrict__ Wkb,
    const __hip_bfloat16* __restrict__ Wvb,
    __hip_bfloat16* __restrict__ Qo, __hip_bfloat16* __restrict__ Ko,
    __hip_bfloat16* __restrict__ Vo)
{
    const __hip_bfloat16* W = (blockIdx.z == 0) ? Wqb : (blockIdx.z == 1 ? Wkb : Wvb);
    __hip_bfloat16*       O = (blockIdx.z == 0) ? Qo  : (blockIdx.z == 1 ? Ko  : Vo);

    __shared__ __align__(16) char Al[128 * 64 * 2];   // [row][64 bf16], 128B rows
    __shared__ __align__(16) char Bl[128 * 64 * 2];

    const int t  = threadIdx.x;
    const int w  = t >> 6, l = t & 63;
    const int li = l & 15, hi4 = l >> 4;
    const int wr = w >> 1, wc = w & 1;
    const int m0 = blockIdx.y * 128;
    const int n0 = blockIdx.x * 128;

    // staging: chunk = w*4+c (0..15), 1KB each = 8 rows. lane l -> row chunk*8+(l>>3),
    // source col pre-swizzled so linear LDS ends up XOR-swizzled.
    const int srow = l >> 3;                       // row within chunk
    const int scol = ((l & 7) ^ (l >> 3)) * 8;     // bf16 col (pre-swizzled)

    f32x4 acc[4][4];
    #pragma unroll
    for (int i = 0; i < 4; ++i)
        #pragma unroll
        for (int j = 0; j < 4; ++j)
            #pragma unroll
            for (int r = 0; r < 4; ++r) acc[i][j][r] = 0.f;

    for (int k0 = 0; k0 < D_; k0 += 64) {
        if (k0) __syncthreads();
        #pragma unroll
        for (int c = 0; c < 4; ++c) {
            const int chunk = w * 4 + c;           // 0..15
            const int row   = chunk * 8 + srow;
            gld_lds16(X + (size_t)(m0 + row) * D_ + k0 + scol, Al + chunk * 1024);
            gld_lds16(W + (size_t)(n0 + row) * D_ + k0 + scol, Bl + chunk * 1024);
        }
        __syncthreads();

        #pragma unroll
        for (int s = 0; s < 2; ++s) {
            const int cbA = (s * 64 + hi4 * 16) ^ ((li & 7) << 4);  // row-bit = li&7
            short8 af[4], bf[4];
            #pragma unroll
            for (int mi = 0; mi < 4; ++mi)
                af[mi] = *(const short8*)(Al + (wr * 64 + mi * 16 + li) * 128 + cbA);
            #pragma unroll
            for (int ni = 0; ni < 4; ++ni)
                bf[ni] = *(const short8*)(Bl + (wc * 64 + ni * 16 + li) * 128 + cbA);
            #pragma unroll
            for (int mi = 0; mi < 4; ++mi)
                #pragma unroll
                for (int ni = 0; ni < 4; ++ni)
                    acc[mi][ni] = __builtin_amdgcn_mfma_f32_16x16x32_bf16(
                        af[mi], bf[ni], acc[mi][ni], 0, 0, 0);
        }
    }

    // epilogue: C[r]: row = (l>>4)*4 + r, col = l&15
    #pragma unroll
    for (int mi = 0; mi < 4; ++mi) {
        #pragma unroll
        for (int ni = 0; ni < 4; ++ni) {
            const int n  = n0 + wc * 64 + ni * 16 + li;
            const int h  = n >> 7, hd = n & (HD_ - 1);
            #pragma unroll
            for (int r = 0; r < 4; ++r) {
                const int m = m0 + wr * 64 + mi * 16 + hi4 * 4 + r;
                const int b = m >> 11, ml = m & (L_ - 1);
                O[((size_t)(b * H_ + h) * L_ + ml) * HD_ + hd] =
                    __float2bfloat16(acc[mi][ni][r]);
            }
        }
    }
}

// ---------------------------------------------------------------------------
// Retention (bf16 MFMA): out[b,h,i,:] = sum_{j<=i} (q_i.k_j)*scale*g^(i-j) v_j
// (unchanged from the round-2 passing version)
// ---------------------------------------------------------------------------
__global__ __launch_bounds__(256) void retn_kernel(
    const __hip_bfloat16* __restrict__ Qb, const __hip_bfloat16* __restrict__ Kb,
    const __hip_bfloat16* __restrict__ Vb, const float* __restrict__ gl,
    float* __restrict__ out)
{
    const int bid = blockIdx.x;
    const int m   = 15 - (bid >> 5);        // heavy blocks dispatched first
    const int bh  = bid & 31;
    const int b   = bh >> 4, h = bh & (H_ - 1);
    const int t   = threadIdx.x;
    const int w   = t >> 6, l = t & 63;
    const int li  = l & 31, hi = l >> 5;

    const float gamma = 1.f / (1.f + __expf(-gl[h]));
    const float lg2   = __log2f(gamma);
    const float scale = 0.08838834764831845f;   // 128^-0.5

    __shared__ __align__(16) char Kls[32 * 128 * 2];            // XOR-swizzled rows
    __shared__ __align__(16) unsigned short Vt[128 * 40];       // [d][j] padded

    const size_t base = (size_t)bh * (L_ * HD_);
    const int i0 = m * 128 + w * 32;          // this wave's first Q row

    // hoist Q fragments: B-operand for S^T (col = li, k = hd slice)
    short8 qf[8];
    {
        const __hip_bfloat16* qrow = Qb + base + (size_t)(i0 + li) * HD_;
        #pragma unroll
        for (int s = 0; s < 8; ++s)
            qf[s] = *(const short8*)(qrow + s * 16 + hi * 8);
    }

    // per-lane decay factors gamma^(i_loc - j_loc) for the 16 C-regs
    float df[16];
    #pragma unroll
    for (int r = 0; r < 16; ++r) {
        const int jl = (r & 3) + 8 * (r >> 2) + 4 * hi;
        df[r] = exp2f(lg2 * (float)(li - jl));
    }

    f32x16 acc[4];
    #pragma unroll
    for (int c = 0; c < 4; ++c)
        #pragma unroll
        for (int r = 0; r < 16; ++r) acc[c][r] = 0.f;

    const int jmax = m * 128 + 96;            // block max wave i0
    for (int j0 = 0; j0 <= jmax; j0 += 32) {
        if (j0) __syncthreads();
        // stage K (swizzled) and V (transposed), 2 passes x 256 thr x 16B
        #pragma unroll
        for (int p = 0; p < 2; ++p) {
            const int tt = p * 256 + t;
            const int jr = tt >> 4, seg = tt & 15;
            int4 kv = *(const int4*)(Kb + base + (size_t)(j0 + jr) * HD_ + seg * 8);
            *(int4*)(Kls + jr * 256 + ((seg * 16) ^ ((jr & 7) << 4))) = kv;
            int4 vv = *(const int4*)(Vb + base + (size_t)(j0 + jr) * HD_ + seg * 8);
            const unsigned short* pv = (const unsigned short*)&vv;
            #pragma unroll
            for (int e = 0; e < 8; ++e)
                Vt[(seg * 8 + e) * 40 + jr] = pv[e];
        }
        __syncthreads();

        if (j0 > i0) continue;                // causal skip (barriers stay uniform)

        // QK^T: S^T[j,i], j = C-rows, i = C-col (= li)
        f32x16 c;
        #pragma unroll
        for (int r = 0; r < 16; ++r) c[r] = 0.f;
        #pragma unroll
        for (int s = 0; s < 8; ++s) {
            short8 kf = *(const short8*)(Kls + li * 256 +
                                         ((s * 32 + hi * 16) ^ ((li & 7) << 4)));
            c = __builtin_amdgcn_mfma_f32_32x32x16_bf16(kf, qf[s], c, 0, 0, 0);
        }

        // decay (+ diagonal mask)
        float p[16];
        const float bt = exp2f(lg2 * (float)(i0 - j0)) * scale;
        if (j0 == i0) {
            #pragma unroll
            for (int r = 0; r < 16; ++r) {
                const int jl = (r & 3) + 8 * (r >> 2) + 4 * hi;
                p[r] = (jl <= li) ? c[r] * (df[r] * bt) : 0.f;
            }
        } else {
            #pragma unroll
            for (int r = 0; r < 16; ++r) p[r] = c[r] * (df[r] * bt);
        }

        // two k-slices (j 0..15 from regs 0..7, j 16..31 from regs 8..15)
        #pragma unroll
        for (int sl = 0; sl < 2; ++sl) {
            const int o = sl * 8;
            unsigned pk01 = pk2(p[o + 0], p[o + 1]);
            unsigned pk23 = pk2(p[o + 2], p[o + 3]);
            unsigned pk45 = pk2(p[o + 4], p[o + 5]);
            unsigned pk67 = pk2(p[o + 6], p[o + 7]);
            unsigned x01 = (unsigned)__shfl_xor((int)pk01, 32);
            unsigned x23 = (unsigned)__shfl_xor((int)pk23, 32);
            unsigned x45 = (unsigned)__shfl_xor((int)pk45, 32);
            unsigned x67 = (unsigned)__shfl_xor((int)pk67, 32);
            union { short8 v; unsigned u[4]; } pf;
            pf.u[0] = hi ? x45 : pk01;
            pf.u[1] = hi ? x67 : pk23;
            pf.u[2] = hi ? pk45 : x01;
            pf.u[3] = hi ? pk67 : x23;
            #pragma unroll
            for (int cch = 0; cch < 4; ++cch) {
                short8 vf = *(const short8*)(Vt + (cch * 32 + li) * 40 + sl * 16 + hi * 8);
                acc[cch] = __builtin_amdgcn_mfma_f32_32x32x16_bf16(
                    pf.v, vf, acc[cch], 0, 0, 0);
            }
        }
    }

    // epilogue
    #pragma unroll
    for (int cch = 0; cch < 4; ++cch) {
        #pragma unroll
        for (int r = 0; r < 16; ++r) {
            const int row = (r & 3) + 8 * (r >> 2) + 4 * hi;
            out[(size_t)(b * L_ + i0 + row) * D_ + h * HD_ + cch * 32 + li] =
                acc[cch][r];
        }
    }
}

// ---------------------------------------------------------------------------
// GroupNorm, two-pass full-chip: stats (512 blocks) + apply (2048 blocks)
// ---------------------------------------------------------------------------
__global__ __launch_bounds__(256) void gn_stats(
    const float* __restrict__ out, float2* __restrict__ part)
{
    const int bh = blockIdx.x, sl = blockIdx.y;    // (32, 16)
    const int b = bh >> 4, h = bh & (H_ - 1);
    const int t = threadIdx.x;

    float s = 0.f, sq = 0.f;
    #pragma unroll 4
    for (int it = 0; it < 16; ++it) {
        const int n  = it * 256 + t;               // float4 index in slice (4096)
        const int ll = n >> 5, d4 = n & 31;        // 32 float4 per row
        float4 v = *(const float4*)&out[(size_t)(b * L_ + sl * 128 + ll) * D_ + h * HD_ + d4 * 4];
        s  += v.x + v.y + v.z + v.w;
        sq += v.x * v.x + v.y * v.y + v.z * v.z + v.w * v.w;
    }
    #pragma unroll
    for (int off = 32; off > 0; off >>= 1) {
        s  += __shfl_down(s, off);
        sq += __shfl_down(sq, off);
    }
    __shared__ float rs[4], rq[4];
    const int wv = t >> 6, lane = t & 63;
    if (lane == 0) { rs[wv] = s; rq[wv] = sq; }
    __syncthreads();
    if (t == 0)
        part[bh * 16 + sl] = make_float2(rs[0] + rs[1] + rs[2] + rs[3],
                                         rq[0] + rq[1] + rq[2] + rq[3]);
}

__global__ __launch_bounds__(256) void gn_apply(
    float* __restrict__ out, const float2* __restrict__ part,
    const float* __restrict__ gw, const float* __restrict__ gb)
{
    const int bh = blockIdx.x, sl = blockIdx.y;    // (32, 64): 32-row slices
    const int b = bh >> 4, h = bh & (H_ - 1);
    const int t = threadIdx.x;

    float S = 0.f, SQ = 0.f;
    #pragma unroll
    for (int i = 0; i < 16; ++i) {
        float2 p = part[bh * 16 + i];
        S += p.x; SQ += p.y;
    }
    const float inv  = 1.f / (float)(L_ * HD_);
    const float mean = S * inv;
    float var = SQ * inv - mean * mean;
    if (var < 0.f) var = 0.f;
    const float rstd = rsqrtf(var + EPS_);

    #pragma unroll
    for (int it = 0; it < 4; ++it) {
        const int n  = it * 256 + t;               // float4 index in slice (1024)
        const int ll = n >> 5, d4 = n & 31;
        const size_t idx = (size_t)(b * L_ + sl * 32 + ll) * D_ + h * HD_ + d4 * 4;
        float4 v = *(const float4*)&out[idx];
        const float4 w4 = *(const float4*)&gw[h * HD_ + d4 * 4];
        const float4 b4 = *(const float4*)&gb[h * HD_ + d4 * 4];
        v.x = (v.x - mean) * rstd * w4.x + b4.x;
        v.y = (v.y - mean) * rstd * w4.y + b4.y;
        v.z = (v.z - mean) * rstd * w4.z + b4.z;
        v.w = (v.w - mean) * rstd * w4.w + b4.w;
        *(float4*)&out[idx] = v;
    }
}

// ---------------------------------------------------------------------------
extern "C" void kernel_launch(void* const* d_in, const int* in_sizes, int n_in,
                              void* d_out, int out_size, void* d_ws, size_t ws_size,
                              hipStream_t stream) {
    const float* x  = (const float*)d_in[0];
    const float* Wq = (const float*)d_in[1];
    const float* Wk = (const float*)d_in[2];
    const float* Wv = (const float*)d_in[3];
    const float* gl = (const float*)d_in[4];
    const float* gw = (const float*)d_in[5];
    const float* gb = (const float*)d_in[6];
    float* out = (float*)d_out;

    __hip_bfloat16* ws = (__hip_bfloat16*)d_ws;
    __hip_bfloat16* xb  = ws;                    // 8,388,608
    __hip_bfloat16* Wqb = xb  + 8388608;         // 4,194,304 each
    __hip_bfloat16* Wkb = Wqb + 4194304;
    __hip_bfloat16* Wvb = Wkb + 4194304;
    __hip_bfloat16* Qbf = Wvb + 4194304;         // 8,388,608 each
    __hip_bfloat16* Kbf = Qbf + 8388608;
    __hip_bfloat16* Vbf = Kbf + 8388608;
    float2* part = (float2*)(Vbf + 8388608);     // 512 float2

    cast4_kernel<<<2048, 256, 0, stream>>>(x, Wq, Wk, Wv, xb);

    dim3 pgrid(D_ / 128, (B_ * L_) / 128, 3);
    proj_bf16<<<pgrid, 256, 0, stream>>>(xb, Wqb, Wkb, Wvb, Qbf, Kbf, Vbf);

    retn_kernel<<<dim3(512), 256, 0, stream>>>(Qbf, Kbf, Vbf, gl, out);

    gn_stats<<<dim3(32, 16), 256, 0, stream>>>(out, part);
    gn_apply<<<dim3(32, 64), 256, 0, stream>>>(out, part, gw, gb);
}

// Round 5
// 224.861 us; speedup vs baseline: 15.4203x; 1.2468x over previous
//
#include <hip/hip_runtime.h>
#include <hip/hip_bf16.h>
#include <math.h>

#define B_  2
#define L_  2048
#define D_  2048
#define H_  16
#define HD_ 128
#define EPS_ 1e-5f

typedef __attribute__((ext_vector_type(8)))  short short8;
typedef __attribute__((ext_vector_type(4)))  float f32x4;
typedef __attribute__((ext_vector_type(16))) float f32x16;

static __device__ inline unsigned short bfb(float x) {
    __hip_bfloat16 h = __float2bfloat16(x);
    unsigned short s;
    __builtin_memcpy(&s, &h, 2);
    return s;
}
static __device__ inline unsigned pk2(float a, float b) {
    return (unsigned)bfb(a) | ((unsigned)bfb(b) << 16);
}

// direct-to-LDS 16B copy: LDS dest = wave-uniform base + lane*16
static __device__ __forceinline__ void gld_lds16(const void* g, void* l) {
    __builtin_amdgcn_global_load_lds(
        (const __attribute__((address_space(1))) unsigned int*)g,
        (__attribute__((address_space(3))) unsigned int*)l,
        16, 0, 0);
}

// ---------------------------------------------------------------------------
// fused cast f32 -> bf16 for x, Wq, Wk, Wv (dsts contiguous in ws)
// ---------------------------------------------------------------------------
#define XN4 2097152              // 8388608/4
#define WN4 1048576              // 4194304/4
#define TOT4 (XN4 + 3 * WN4)     // 5242880

__global__ __launch_bounds__(256) void cast4_kernel(
    const float* __restrict__ x,  const float* __restrict__ Wq,
    const float* __restrict__ Wk, const float* __restrict__ Wv,
    __hip_bfloat16* __restrict__ dst)
{
    int i = blockIdx.x * 256 + threadIdx.x;
    const int st = gridDim.x * 256;
    for (; i < TOT4; i += st) {
        const float* s;
        int off;
        if (i < XN4)                { s = x;  off = i; }
        else if (i < XN4 + WN4)     { s = Wq; off = i - XN4; }
        else if (i < XN4 + 2 * WN4) { s = Wk; off = i - XN4 - WN4; }
        else                        { s = Wv; off = i - XN4 - 2 * WN4; }
        float4 v = ((const float4*)s)[off];
        uint2 r;
        r.x = pk2(v.x, v.y);
        r.y = pk2(v.z, v.w);
        ((uint2*)dst)[i] = r;
    }
}

// ---------------------------------------------------------------------------
// Projection GEMM (bf16 MFMA): Out[m,n] = sum_k X[m,k] * W[n,k]
// 128x128 tile, BK=64, 4 waves, global_load_lds staging + XOR swizzle.
// z==0/1 (Q,K): write [b,h,l,hd].  z==2 (V): write TRANSPOSED [b,h,hd,l].
// ---------------------------------------------------------------------------
__global__ __launch_bounds__(256) void proj_bf16(
    const __hip_bfloat16* __restrict__ X,
    const __hip_bfloat16* __restrict__ Wqb, const __hip_bfloat16* __restrict__ Wkb,
    const __hip_bfloat16* __restrict__ Wvb,
    __hip_bfloat16* __restrict__ Qo, __hip_bfloat16* __restrict__ Ko,
    __hip_bfloat16* __restrict__ Vt)
{
    const __hip_bfloat16* W = (blockIdx.z == 0) ? Wqb : (blockIdx.z == 1 ? Wkb : Wvb);
    __hip_bfloat16*       O = (blockIdx.z == 0) ? Qo  : (blockIdx.z == 1 ? Ko  : Vt);

    __shared__ __align__(16) char Al[128 * 64 * 2];   // [row][64 bf16], 128B rows
    __shared__ __align__(16) char Bl[128 * 64 * 2];

    const int t  = threadIdx.x;
    const int w  = t >> 6, l = t & 63;
    const int li = l & 15, hi4 = l >> 4;
    const int wr = w >> 1, wc = w & 1;
    const int m0 = blockIdx.y * 128;
    const int n0 = blockIdx.x * 128;

    const int srow = l >> 3;                       // row within chunk
    const int scol = ((l & 7) ^ (l >> 3)) * 8;     // bf16 col (pre-swizzled)

    f32x4 acc[4][4];
    #pragma unroll
    for (int i = 0; i < 4; ++i)
        #pragma unroll
        for (int j = 0; j < 4; ++j)
            #pragma unroll
            for (int r = 0; r < 4; ++r) acc[i][j][r] = 0.f;

    for (int k0 = 0; k0 < D_; k0 += 64) {
        if (k0) __syncthreads();
        #pragma unroll
        for (int c = 0; c < 4; ++c) {
            const int chunk = w * 4 + c;           // 0..15
            const int row   = chunk * 8 + srow;
            gld_lds16(X + (size_t)(m0 + row) * D_ + k0 + scol, Al + chunk * 1024);
            gld_lds16(W + (size_t)(n0 + row) * D_ + k0 + scol, Bl + chunk * 1024);
        }
        __syncthreads();

        #pragma unroll
        for (int s = 0; s < 2; ++s) {
            const int cbA = (s * 64 + hi4 * 16) ^ ((li & 7) << 4);  // row-bit = li&7
            short8 af[4], bf[4];
            #pragma unroll
            for (int mi = 0; mi < 4; ++mi)
                af[mi] = *(const short8*)(Al + (wr * 64 + mi * 16 + li) * 128 + cbA);
            #pragma unroll
            for (int ni = 0; ni < 4; ++ni)
                bf[ni] = *(const short8*)(Bl + (wc * 64 + ni * 16 + li) * 128 + cbA);
            #pragma unroll
            for (int mi = 0; mi < 4; ++mi)
                #pragma unroll
                for (int ni = 0; ni < 4; ++ni)
                    acc[mi][ni] = __builtin_amdgcn_mfma_f32_16x16x32_bf16(
                        af[mi], bf[ni], acc[mi][ni], 0, 0, 0);
        }
    }

    // epilogue: C[r]: row = (l>>4)*4 + r, col = l&15
    if (blockIdx.z == 2) {
        // V transposed: VT[b][n = h*HD+hd][l] ; per lane 4 consecutive l -> 8B store
        #pragma unroll
        for (int mi = 0; mi < 4; ++mi) {
            #pragma unroll
            for (int ni = 0; ni < 4; ++ni) {
                const int n     = n0 + wc * 64 + ni * 16 + li;
                const int mbase = m0 + wr * 64 + mi * 16 + hi4 * 4;
                const int b = mbase >> 11, ml = mbase & (L_ - 1);
                uint2 w2;
                w2.x = pk2(acc[mi][ni][0], acc[mi][ni][1]);
                w2.y = pk2(acc[mi][ni][2], acc[mi][ni][3]);
                *(uint2*)&O[((size_t)b * (H_ * HD_) + n) * L_ + ml] = w2;
            }
        }
    } else {
        #pragma unroll
        for (int mi = 0; mi < 4; ++mi) {
            #pragma unroll
            for (int ni = 0; ni < 4; ++ni) {
                const int n  = n0 + wc * 64 + ni * 16 + li;
                const int h  = n >> 7, hd = n & (HD_ - 1);
                #pragma unroll
                for (int r = 0; r < 4; ++r) {
                    const int m = m0 + wr * 64 + mi * 16 + hi4 * 4 + r;
                    const int b = m >> 11, ml = m & (L_ - 1);
                    O[((size_t)(b * H_ + h) * L_ + ml) * HD_ + hd] =
                        __float2bfloat16(acc[mi][ni][r]);
                }
            }
        }
    }
}

// ---------------------------------------------------------------------------
// Retention (bf16 MFMA): out[b,h,i,:] = sum_{j<=i} (q_i.k_j)*scale*g^(i-j) v_j
// Block = (bh, 128 Q rows), 4 waves x 32 rows.  K and V^T staged per 128-j
// group via global_load_lds (async, linear dest) with 16-slot XOR swizzle
// (slot ^= row&15) applied on the pre-swizzled global source AND the reads.
// Inner 4-subtile loop is barrier-free; causal skip is a per-wave break.
// ---------------------------------------------------------------------------
__global__ __launch_bounds__(256) void retn_kernel(
    const __hip_bfloat16* __restrict__ Qb, const __hip_bfloat16* __restrict__ Kb,
    const __hip_bfloat16* __restrict__ VT, const float* __restrict__ gl,
    float* __restrict__ out)
{
    const int bid = blockIdx.x;
    const int mm  = bid >> 5;
    const int m   = (mm < 8) ? (15 - mm) : (mm - 8);   // pairs sum to 15 per CU
    const int bh  = bid & 31;
    const int b   = bh >> 4, h = bh & (H_ - 1);
    const int t   = threadIdx.x;
    const int w   = t >> 6, l = t & 63;
    const int li  = l & 31, hi = l >> 5;

    const float gamma = 1.f / (1.f + __expf(-gl[h]));
    const float lg2   = __log2f(gamma);
    const float scale = 0.08838834764831845f;   // 128^-0.5

    __shared__ __align__(16) char Klds[32768];   // [128 j][128 e] swizzled
    __shared__ __align__(16) char Vlds[32768];   // [128 d][128 j] swizzled

    const size_t base = (size_t)bh * (L_ * HD_);
    const __hip_bfloat16* VTg = VT + (size_t)bh * (HD_ * L_);
    const int i0 = m * 128 + w * 32;            // this wave's first Q row

    // hoist Q fragments: B-operand for S^T (col = li, k slices)
    short8 qf[8];
    {
        const __hip_bfloat16* qrow = Qb + base + (size_t)(i0 + li) * HD_;
        #pragma unroll
        for (int s = 0; s < 8; ++s)
            qf[s] = *(const short8*)(qrow + s * 16 + hi * 8);
    }

    // per-lane decay factors gamma^(i_loc - j_loc) for the 16 C-regs
    float df[16];
    #pragma unroll
    for (int r = 0; r < 16; ++r) {
        const int jl = (r & 3) + 8 * (r >> 2) + 4 * hi;
        df[r] = exp2f(lg2 * (float)(li - jl));
    }

    f32x16 acc[4];
    #pragma unroll
    for (int c = 0; c < 4; ++c)
        #pragma unroll
        for (int r = 0; r < 16; ++r) acc[c][r] = 0.f;

    const int srow4 = l >> 4;        // 0..3 row-within-chunk
    const int sslot = l & 15;        // 16B slot

    for (int gj = 0; gj <= m * 128; gj += 128) {
        __syncthreads();             // prev group fully consumed
        #pragma unroll
        for (int cc = 0; cc < 8; ++cc) {
            const int c  = w * 8 + cc;            // chunk 0..31 (4 rows each)
            const int r  = c * 4 + srow4;         // row 0..127
            const int sc = ((sslot ^ (r & 15)) * 8);
            gld_lds16(Kb + base + (size_t)(gj + r) * HD_ + sc, Klds + c * 1024);
            gld_lds16(VTg + (size_t)r * L_ + gj + sc,          Vlds + c * 1024);
        }
        __syncthreads();             // (compiler drains vmcnt before barrier)

        const int tmax = ((i0 - gj) >> 5) < 3 ? ((i0 - gj) >> 5) : 3;
        for (int jt = 0; jt <= tmax; ++jt) {
            const int j0 = gj + jt * 32;

            // QK^T: S^T[j,i], j = C-rows, i = C-col (= li)
            f32x16 c;
            #pragma unroll
            for (int r = 0; r < 16; ++r) c[r] = 0.f;
            #pragma unroll
            for (int s = 0; s < 8; ++s) {
                short8 kf = *(const short8*)(Klds + (jt * 32 + li) * 256 +
                                             (((s * 2 + hi) ^ (li & 15)) << 4));
                c = __builtin_amdgcn_mfma_f32_32x32x16_bf16(kf, qf[s], c, 0, 0, 0);
            }

            // decay (+ diagonal mask)
            float p[16];
            const float bt = exp2f(lg2 * (float)(i0 - j0)) * scale;
            if (j0 == i0) {
                #pragma unroll
                for (int r = 0; r < 16; ++r) {
                    const int jl = (r & 3) + 8 * (r >> 2) + 4 * hi;
                    p[r] = (jl <= li) ? c[r] * (df[r] * bt) : 0.f;
                }
            } else {
                #pragma unroll
                for (int r = 0; r < 16; ++r) p[r] = c[r] * (df[r] * bt);
            }

            // two k-slices (j 0..15 from regs 0..7, j 16..31 from regs 8..15)
            #pragma unroll
            for (int sl = 0; sl < 2; ++sl) {
                const int o = sl * 8;
                unsigned pk01 = pk2(p[o + 0], p[o + 1]);
                unsigned pk23 = pk2(p[o + 2], p[o + 3]);
                unsigned pk45 = pk2(p[o + 4], p[o + 5]);
                unsigned pk67 = pk2(p[o + 6], p[o + 7]);
                unsigned x01 = (unsigned)__shfl_xor((int)pk01, 32);
                unsigned x23 = (unsigned)__shfl_xor((int)pk23, 32);
                unsigned x45 = (unsigned)__shfl_xor((int)pk45, 32);
                unsigned x67 = (unsigned)__shfl_xor((int)pk67, 32);
                union { short8 v; unsigned u[4]; } pf;
                pf.u[0] = hi ? x45 : pk01;
                pf.u[1] = hi ? x67 : pk23;
                pf.u[2] = hi ? pk45 : x01;
                pf.u[3] = hi ? pk67 : x23;
                #pragma unroll
                for (int cch = 0; cch < 4; ++cch) {
                    short8 vf = *(const short8*)(Vlds + (cch * 32 + li) * 256 +
                                 (((jt * 4 + sl * 2 + hi) ^ (li & 15)) << 4));
                    acc[cch] = __builtin_amdgcn_mfma_f32_32x32x16_bf16(
                        pf.v, vf, acc[cch], 0, 0, 0);
                }
            }
        }
    }

    // epilogue: acc[cch] C-layout: col d = cch*32+li, row = (r&3)+8*(r>>2)+4*hi
    #pragma unroll
    for (int cch = 0; cch < 4; ++cch) {
        #pragma unroll
        for (int r = 0; r < 16; ++r) {
            const int row = (r & 3) + 8 * (r >> 2) + 4 * hi;
            out[(size_t)(b * L_ + i0 + row) * D_ + h * HD_ + cch * 32 + li] =
                acc[cch][r];
        }
    }
}

// ---------------------------------------------------------------------------
// GroupNorm, two-pass full-chip: stats (512 blocks) + apply (2048 blocks)
// ---------------------------------------------------------------------------
__global__ __launch_bounds__(256) void gn_stats(
    const float* __restrict__ out, float2* __restrict__ part)
{
    const int bh = blockIdx.x, sl = blockIdx.y;    // (32, 16)
    const int b = bh >> 4, h = bh & (H_ - 1);
    const int t = threadIdx.x;

    float s = 0.f, sq = 0.f;
    #pragma unroll 4
    for (int it = 0; it < 16; ++it) {
        const int n  = it * 256 + t;               // float4 index in slice (4096)
        const int ll = n >> 5, d4 = n & 31;        // 32 float4 per row
        float4 v = *(const float4*)&out[(size_t)(b * L_ + sl * 128 + ll) * D_ + h * HD_ + d4 * 4];
        s  += v.x + v.y + v.z + v.w;
        sq += v.x * v.x + v.y * v.y + v.z * v.z + v.w * v.w;
    }
    #pragma unroll
    for (int off = 32; off > 0; off >>= 1) {
        s  += __shfl_down(s, off);
        sq += __shfl_down(sq, off);
    }
    __shared__ float rs[4], rq[4];
    const int wv = t >> 6, lane = t & 63;
    if (lane == 0) { rs[wv] = s; rq[wv] = sq; }
    __syncthreads();
    if (t == 0)
        part[bh * 16 + sl] = make_float2(rs[0] + rs[1] + rs[2] + rs[3],
                                         rq[0] + rq[1] + rq[2] + rq[3]);
}

__global__ __launch_bounds__(256) void gn_apply(
    float* __restrict__ out, const float2* __restrict__ part,
    const float* __restrict__ gw, const float* __restrict__ gb)
{
    const int bh = blockIdx.x, sl = blockIdx.y;    // (32, 64): 32-row slices
    const int b = bh >> 4, h = bh & (H_ - 1);
    const int t = threadIdx.x;

    float S = 0.f, SQ = 0.f;
    #pragma unroll
    for (int i = 0; i < 16; ++i) {
        float2 p = part[bh * 16 + i];
        S += p.x; SQ += p.y;
    }
    const float inv  = 1.f / (float)(L_ * HD_);
    const float mean = S * inv;
    float var = SQ * inv - mean * mean;
    if (var < 0.f) var = 0.f;
    const float rstd = rsqrtf(var + EPS_);

    #pragma unroll
    for (int it = 0; it < 4; ++it) {
        const int n  = it * 256 + t;               // float4 index in slice (1024)
        const int ll = n >> 5, d4 = n & 31;
        const size_t idx = (size_t)(b * L_ + sl * 32 + ll) * D_ + h * HD_ + d4 * 4;
        float4 v = *(const float4*)&out[idx];
        const float4 w4 = *(const float4*)&gw[h * HD_ + d4 * 4];
        const float4 b4 = *(const float4*)&gb[h * HD_ + d4 * 4];
        v.x = (v.x - mean) * rstd * w4.x + b4.x;
        v.y = (v.y - mean) * rstd * w4.y + b4.y;
        v.z = (v.z - mean) * rstd * w4.z + b4.z;
        v.w = (v.w - mean) * rstd * w4.w + b4.w;
        *(float4*)&out[idx] = v;
    }
}

// ---------------------------------------------------------------------------
extern "C" void kernel_launch(void* const* d_in, const int* in_sizes, int n_in,
                              void* d_out, int out_size, void* d_ws, size_t ws_size,
                              hipStream_t stream) {
    const float* x  = (const float*)d_in[0];
    const float* Wq = (const float*)d_in[1];
    const float* Wk = (const float*)d_in[2];
    const float* Wv = (const float*)d_in[3];
    const float* gl = (const float*)d_in[4];
    const float* gw = (const float*)d_in[5];
    const float* gb = (const float*)d_in[6];
    float* out = (float*)d_out;

    __hip_bfloat16* ws = (__hip_bfloat16*)d_ws;
    __hip_bfloat16* xb  = ws;                    // 8,388,608
    __hip_bfloat16* Wqb = xb  + 8388608;         // 4,194,304 each
    __hip_bfloat16* Wkb = Wqb + 4194304;
    __hip_bfloat16* Wvb = Wkb + 4194304;
    __hip_bfloat16* Qbf = Wvb + 4194304;         // 8,388,608 each
    __hip_bfloat16* Kbf = Qbf + 8388608;
    __hip_bfloat16* VTb = Kbf + 8388608;         // V transposed [b,h,d,l]
    float2* part = (float2*)(VTb + 8388608);     // 512 float2

    cast4_kernel<<<2048, 256, 0, stream>>>(x, Wq, Wk, Wv, xb);

    dim3 pgrid(D_ / 128, (B_ * L_) / 128, 3);
    proj_bf16<<<pgrid, 256, 0, stream>>>(xb, Wqb, Wkb, Wvb, Qbf, Kbf, VTb);

    retn_kernel<<<dim3(512), 256, 0, stream>>>(Qbf, Kbf, VTb, gl, out);

    gn_stats<<<dim3(32, 16), 256, 0, stream>>>(out, part);
    gn_apply<<<dim3(32, 64), 256, 0, stream>>>(out, part, gw, gb);
}